// Round 7
// baseline (173.123 us; speedup 1.0000x reference)
//
#include <hip/hip_runtime.h>
#include <math.h>

#define SEQ    4096
#define DH     64
#define DMODEL 1024
#define NBH    32
#define NT64   64               // 64-key tiles per bh
#define LOG2E  1.44269504088896340736f

typedef __attribute__((ext_vector_type(8)))  short short8;
typedef __attribute__((ext_vector_type(4)))  float f32x4;
typedef __attribute__((ext_vector_type(16))) float f32x16;
typedef __attribute__((ext_vector_type(2)))  unsigned uint2v;

// ws layout (bytes):
//   [0, 33554432)            KV fragments: 32 bh x 64 tiles x 8192 B (K|V)
//   [33554432, 67108864)     bf16 partials: 2048 pid x 16384 B (128q x 64d)
//   [67108864, 68157440)     f32 lsums: 2048 pid x 512 B (128 q)
#define WS_KV_BYTES   33554432ull
#define WS_NEED_SPLIT 68157440ull

__device__ __forceinline__ unsigned short f2bf(float f) {
  union { float f; unsigned u; } x; x.f = f;
  unsigned r = x.u + 0x7FFFu + ((x.u >> 16) & 1u);   // RNE
  return (unsigned short)(r >> 16);
}
__device__ __forceinline__ float bf2f(unsigned short u) {
  union { unsigned u; float f; } x; x.u = ((unsigned)u) << 16;
  return x.f;
}
__device__ __forceinline__ unsigned cvtpk_bf16(float lo, float hi) {
  unsigned r;
  asm("v_cvt_pk_bf16_f32 %0, %1, %2" : "=v"(r) : "v"(lo), "v"(hi));
  return r;
}

// ---------------------------------------------------------------------------
// Prepass (verified R5/R6): bf16 K/V in MFMA-fragment order, per 64-key tile
// (16 KB: K 8KB | V 8KB). fattn ds_reads become wave-linear.
// ---------------------------------------------------------------------------
__global__ __launch_bounds__(256)
void prep(const float* __restrict__ Kp, const float* __restrict__ Vp,
          unsigned short* __restrict__ ws) {
  __shared__ unsigned short Kt[128 * DH];
  __shared__ unsigned short Vt[128 * DH];
  const int blk = blockIdx.x;              // bh*32 + t128
  const int bh = blk >> 5, t128 = blk & 31;
  const int b = bh >> 4, h = bh & 15;
  const size_t gbase = (size_t)b * SEQ * DMODEL + (size_t)h * DH +
                       (size_t)t128 * 128 * DMODEL;
  const float* Kb = Kp + gbase;
  const float* Vb = Vp + gbase;
  unsigned short* wt = ws + (size_t)bh * NT64 * 8192 + (size_t)(2 * t128) * 8192;
  const int tid = threadIdx.x;

#pragma unroll
  for (int c = 0; c < 8; ++c) {
    const int idx = c * 256 + tid;
    const int row = idx >> 4, dc = idx & 15;
    f32x4 kf = *(const f32x4*)(Kb + (size_t)row * DMODEL + dc * 4);
    f32x4 vf = *(const f32x4*)(Vb + (size_t)row * DMODEL + dc * 4);
    uint2v ku, vu;
    ku[0] = (unsigned)f2bf(kf[0]) | ((unsigned)f2bf(kf[1]) << 16);
    ku[1] = (unsigned)f2bf(kf[2]) | ((unsigned)f2bf(kf[3]) << 16);
    vu[0] = (unsigned)f2bf(vf[0]) | ((unsigned)f2bf(vf[1]) << 16);
    vu[1] = (unsigned)f2bf(vf[2]) | ((unsigned)f2bf(vf[3]) << 16);
    *(uint2v*)&Kt[row * 64 + dc * 4] = ku;
    *(uint2v*)&Vt[row * 64 + dc * 4] = vu;
  }
  __syncthreads();

#pragma unroll
  for (int c = 0; c < 4; ++c) {            // K fragments
    const int idx = c * 256 + tid;
    const int l31 = idx & 31, hi = (idx >> 5) & 1, d4 = (idx >> 6) & 3, kb = idx >> 8;
    const int tau = kb >> 1, kb2 = kb & 1;
    short8 v = *(const short8*)&Kt[(kb * 32 + l31) * 64 + d4 * 16 + hi * 8];
    *(short8*)&wt[tau * 8192 + (((kb2 * 4 + d4) * 2 + hi) * 32 + l31) * 8] = v;
  }
#pragma unroll
  for (int c = 0; c < 4; ++c) {            // V fragments
    const int idx = c * 256 + tid;
    const int l31 = idx & 31, dt = (idx >> 5) & 1, hi = (idx >> 6) & 1, k16 = idx >> 7;
    const int tau = k16 >> 2, k162 = k16 & 3;
    const int d = dt * 32 + l31, kb0 = k16 * 16 + hi * 8;
    short8 v;
#pragma unroll
    for (int j = 0; j < 8; ++j) v[j] = (short)Vt[(kb0 + j) * 64 + d];
    *(short8*)&wt[tau * 8192 + 4096 + (((k162 * 2 + hi) * 64) + dt * 32 + l31) * 8] = v;
  }
}

// ---- QK^T for one 32-key block: 4 wave-linear ds_read + 4 chained MFMA
__device__ __forceinline__ f32x16 qk_block(const char* Lk, int kbpar, int laneK,
                                           const short8* qb, const f32x16& ZERO) {
  short8 ka0 = *(const short8*)(Lk + kbpar * 4096 + 0 * 1024 + laneK);
  short8 ka1 = *(const short8*)(Lk + kbpar * 4096 + 1 * 1024 + laneK);
  short8 ka2 = *(const short8*)(Lk + kbpar * 4096 + 2 * 1024 + laneK);
  short8 ka3 = *(const short8*)(Lk + kbpar * 4096 + 3 * 1024 + laneK);
  f32x16 z;
  __builtin_amdgcn_s_setprio(1);
  z = __builtin_amdgcn_mfma_f32_32x32x16_bf16(ka0, qb[0], ZERO, 0, 0, 0);
  z = __builtin_amdgcn_mfma_f32_32x32x16_bf16(ka1, qb[1], z, 0, 0, 0);
  z = __builtin_amdgcn_mfma_f32_32x32x16_bf16(ka2, qb[2], z, 0, 0, 0);
  z = __builtin_amdgcn_mfma_f32_32x32x16_bf16(ka3, qb[3], z, 0, 0, 0);
  __builtin_amdgcn_s_setprio(0);
  return z;
}

// ---- shift-free softmax + pack + PV for one 32-key score block.
// V fragments passed in registers (v0a/v0b = 16-key slice 0, d 0-31 / 32-63;
// v1a/v1b = slice 1).
__device__ __forceinline__ void proc_core(f32x16& z,
                                          short8 v0a, short8 v0b,
                                          short8 v1a, short8 v1b,
                                          f32x16& accL, f32x16& accH,
                                          float& lsum) {
#pragma unroll
  for (int r = 0; r < 16; ++r) z[r] = __builtin_amdgcn_exp2f(z[r]);
  {
    float s0 = (z[0] + z[1]) + (z[2] + z[3]);
    float s1 = (z[4] + z[5]) + (z[6] + z[7]);
    float s2 = (z[8] + z[9]) + (z[10] + z[11]);
    float s3 = (z[12] + z[13]) + (z[14] + z[15]);
    lsum += (s0 + s1) + (s2 + s3);
  }
#pragma unroll
  for (int s = 0; s < 2; ++s) {
    const int R = 8 * s;
    unsigned a0 = cvtpk_bf16(z[R + 0], z[R + 1]);
    unsigned c0 = cvtpk_bf16(z[R + 4], z[R + 5]);
    unsigned a1 = cvtpk_bf16(z[R + 2], z[R + 3]);
    unsigned c1 = cvtpk_bf16(z[R + 6], z[R + 7]);
    asm("v_permlane32_swap_b32 %0, %1" : "+v"(a0), "+v"(c0));
    asm("v_permlane32_swap_b32 %0, %1" : "+v"(a1), "+v"(c1));
    union { unsigned u[4]; short8 s8; } pw;
    pw.u[0] = a0; pw.u[1] = a1; pw.u[2] = c0; pw.u[3] = c1;
    __builtin_amdgcn_s_setprio(1);
    if (s == 0) {
      accL = __builtin_amdgcn_mfma_f32_32x32x16_bf16(pw.s8, v0a, accL, 0, 0, 0);
      accH = __builtin_amdgcn_mfma_f32_32x32x16_bf16(pw.s8, v0b, accH, 0, 0, 0);
    } else {
      accL = __builtin_amdgcn_mfma_f32_32x32x16_bf16(pw.s8, v1a, accL, 0, 0, 0);
      accH = __builtin_amdgcn_mfma_f32_32x32x16_bf16(pw.s8, v1b, accH, 0, 0, 0);
    }
    __builtin_amdgcn_s_setprio(0);
  }
}

// ---------------------------------------------------------------------------
// Flash attention, single-barrier pipelined tiles:
//   iter t: STAGE(buf^1 <- tile t+1)  [full-tile lead for the vmcnt drain]
//           zE = QK(blk0, cur)
//           proc(zO_prev)             [register-only: V was hoisted]
//           zO = QK(blk1, cur); hoist blk1 V slices (2,3) to regs
//           proc(zE, V slices 0,1 from cur LDS)
//           __syncthreads()           [one barrier per tile]
// 4 waves x 32 q = 128 q/block; KT=64 double-buffered (32 KB LDS).
// SPLIT: halves of KV range -> bf16 partial + f32 lsum (shift-free softmax
// combines exactly).
// ---------------------------------------------------------------------------
template <bool SPLIT>
__global__ __launch_bounds__(256, 3)
void fattn(const float* __restrict__ Qp,
           const unsigned short* __restrict__ ws,
           float* __restrict__ Op) {
  __shared__ __align__(16) char lds[2][16384];   // [buf][K 8KB | V 8KB]

  const int tid  = threadIdx.x;
  const int lane = tid & 63;
  const int w    = tid >> 6;          // 0..3
  const int hi   = lane >> 5;
  const int l31  = lane & 31;

  int bh, qc, sh, rid;
  if (SPLIT) {                        // 2048 wgs: 256/XCD -> 4 bh per XCD
    const int id = blockIdx.x;
    rid = (id & 7) * 256 + (id >> 3);
    bh = rid >> 6; qc = (rid >> 1) & 31; sh = rid & 1;
  } else {                            // 1024 wgs
    const int id = blockIdx.x;
    rid = (id & 7) * 128 + (id >> 3);
    bh = rid >> 5; qc = rid & 31; sh = 0;
  }
  const int NTloc = SPLIT ? 32 : 64;
  const int t0    = sh * 32;
  const int q0    = qc * 128 + w * 32;

  const int b = bh >> 4, h = bh & 15;
  const float* Qb = Qp + (size_t)b * SEQ * DMODEL + (size_t)h * DH;
  const char* wsb = (const char*)(ws + (size_t)bh * NT64 * 8192);

  // Q B-frag (col=q=l31, k: d = d4*16 + hi*8 + i); folds 1/8 * log2e
  short8 qb[4];
  {
    const float* qr = Qb + (size_t)(q0 + l31) * DMODEL;
    const float sc = 0.125f * LOG2E;
#pragma unroll
    for (int d4 = 0; d4 < 4; ++d4) {
      const float* p = qr + d4 * 16 + hi * 8;
      f32x4 f0 = *(const f32x4*)p;
      f32x4 f1 = *(const f32x4*)(p + 4);
      short8 v;
#pragma unroll
      for (int i = 0; i < 4; ++i) {
        v[i]     = (short)f2bf(f0[i] * sc);
        v[i + 4] = (short)f2bf(f1[i] * sc);
      }
      qb[d4] = v;
    }
  }

  f32x16 ZERO;
#pragma unroll
  for (int r = 0; r < 16; ++r) ZERO[r] = 0.f;
  f32x16 accL = ZERO, accH = ZERO;    // O cols d 0-31 / 32-63
  float lsum = 0.f;

  const int laneK = hi * 512 + l31 * 16;
  const int laneV = hi * 1024 + l31 * 16;

#define STAGE(buf_, tau_)                                                     \
  {                                                                           \
    const char* src_ = wsb + (size_t)(tau_) * 16384;                          \
    char* dst_ = &lds[buf_][0];                                               \
    _Pragma("unroll")                                                         \
    for (int c_ = 0; c_ < 4; ++c_) {                                          \
      __builtin_amdgcn_global_load_lds(                                       \
          (const __attribute__((address_space(1))) void*)(src_ + c_ * 4096 +  \
                                                          tid * 16),          \
          (__attribute__((address_space(3))) void*)(dst_ + c_ * 4096 +        \
                                                    tid * 16),                \
          16, 0, 0);                                                          \
    }                                                                         \
  }

  STAGE(0, t0);
  __syncthreads();

  f32x16 zO;                          // carried block-1 scores
  short8 vO0a, vO0b, vO1a, vO1b;      // carried block-1 V fragments (regs)

  for (int t = 0; t < NTloc; ++t) {
    const int cur = t & 1;
    const char* Lk = &lds[cur][0];
    const char* Lv = &lds[cur][8192];

    if (t + 1 < NTloc) STAGE(cur ^ 1, t0 + t + 1);   // earliest possible issue

    f32x16 zE = qk_block(Lk, 0, laneK, qb, ZERO);    // keys 0-31
    if (t > 0)                                       // register-only: overlaps
      proc_core(zO, vO0a, vO0b, vO1a, vO1b, accL, accH, lsum);

    zO = qk_block(Lk, 1, laneK, qb, ZERO);           // keys 32-63
    vO0a = *(const short8*)(Lv + 2 * 2048 + laneV);  // hoist blk1 V to regs
    vO0b = *(const short8*)(Lv + 2 * 2048 + 512 + laneV);
    vO1a = *(const short8*)(Lv + 3 * 2048 + laneV);
    vO1b = *(const short8*)(Lv + 3 * 2048 + 512 + laneV);

    short8 e0a = *(const short8*)(Lv + 0 * 2048 + laneV);
    short8 e0b = *(const short8*)(Lv + 0 * 2048 + 512 + laneV);
    short8 e1a = *(const short8*)(Lv + 1 * 2048 + laneV);
    short8 e1b = *(const short8*)(Lv + 1 * 2048 + 512 + laneV);
    proc_core(zE, e0a, e0b, e1a, e1b, accL, accH, lsum);

    __syncthreads();                                 // one barrier per tile
  }
  proc_core(zO, vO0a, vO0b, vO1a, vO1b, accL, accH, lsum);

  if (SPLIT) {
    unsigned short* part =
        (unsigned short*)((char*)const_cast<unsigned short*>(ws) + WS_KV_BYTES) +
        (size_t)rid * 8192;
    float* lout = (float*)((char*)const_cast<unsigned short*>(ws) +
                           2 * WS_KV_BYTES) + (size_t)rid * 128;
    const float lt = lsum + __shfl_xor(lsum, 32, 64);
    if (hi == 0) lout[w * 32 + l31] = lt;
#pragma unroll
    for (int r = 0; r < 16; ++r) {
      const int qrow = (r & 3) + 8 * (r >> 2) + 4 * hi;
      part[(w * 32 + qrow) * 64 + l31]      = f2bf(accL[r]);
      part[(w * 32 + qrow) * 64 + 32 + l31] = f2bf(accH[r]);
    }
  } else {
    const float lt  = lsum + __shfl_xor(lsum, 32, 64);
    const float inv = 1.0f / lt;
#pragma unroll
    for (int r = 0; r < 16; ++r) {
      const int qrow = (r & 3) + 8 * (r >> 2) + 4 * hi;
      const float iv = __shfl(inv, qrow + (lane & 32), 64);
      const size_t row = (size_t)bh * SEQ + q0 + qrow;
      Op[row * DH + l31]      = accL[r] * iv;
      Op[row * DH + 32 + l31] = accH[r] * iv;
    }
  }
#undef STAGE
}

// ---------------------------------------------------------------------------
// Combine: O = (A0 + A1) / (l0 + l1) over the 2 KV shards.
// ---------------------------------------------------------------------------
__global__ __launch_bounds__(256)
void combine(const unsigned short* __restrict__ ws, float* __restrict__ Op) {
  const unsigned short* part = (const unsigned short*)((const char*)ws + WS_KV_BYTES);
  const float* lsum = (const float*)((const char*)ws + 2 * WS_KV_BYTES);
  const int gid = blockIdx.x * 256 + threadIdx.x;   // 1,048,576 threads
  const int bqc = gid >> 10;                        // 0..1023 (bh*32 + qc)
  const int rem = gid & 1023;
  const int q = rem >> 3, dc = rem & 7;
  const int pid0 = bqc * 2, pid1 = pid0 + 1;
  short8 A0 = *(const short8*)&part[(size_t)pid0 * 8192 + q * 64 + dc * 8];
  short8 A1 = *(const short8*)&part[(size_t)pid1 * 8192 + q * 64 + dc * 8];
  const float l = lsum[pid0 * 128 + q] + lsum[pid1 * 128 + q];
  const float inv = 1.0f / l;
  const int bh = bqc >> 5, qc = bqc & 31;
  float* o = Op + ((size_t)bh * SEQ + qc * 128 + q) * DH + dc * 8;
  f32x4 o0, o1;
#pragma unroll
  for (int j = 0; j < 4; ++j) {
    o0[j] = (bf2f((unsigned short)A0[j]) + bf2f((unsigned short)A1[j])) * inv;
    o1[j] = (bf2f((unsigned short)A0[j + 4]) + bf2f((unsigned short)A1[j + 4])) * inv;
  }
  *(f32x4*)o = o0;
  *(f32x4*)(o + 4) = o1;
}

extern "C" void kernel_launch(void* const* d_in, const int* in_sizes, int n_in,
                              void* d_out, int out_size, void* d_ws, size_t ws_size,
                              hipStream_t stream) {
  const float* Q = (const float*)d_in[0];
  const float* K = (const float*)d_in[1];
  const float* V = (const float*)d_in[2];
  float* O = (float*)d_out;
  unsigned short* ws = (unsigned short*)d_ws;

  prep<<<dim3(NBH * 32), dim3(256), 0, stream>>>(K, V, ws);
  if (ws_size >= WS_NEED_SPLIT) {
    fattn<true><<<dim3(2048), dim3(256), 0, stream>>>(Q, ws, O);
    combine<<<dim3(4096), dim3(256), 0, stream>>>(ws, O);
  } else {
    fattn<false><<<dim3(1024), dim3(256), 0, stream>>>(Q, ws, O);
  }
}

// Round 8
// 168.315 us; speedup vs baseline: 1.0286x; 1.0286x over previous
//
#include <hip/hip_runtime.h>
#include <math.h>

#define SEQ    4096
#define DH     64
#define DMODEL 1024
#define NBH    32
#define NT64   64               // 64-key tiles per bh
#define LOG2E  1.44269504088896340736f

typedef __attribute__((ext_vector_type(8)))  short short8;
typedef __attribute__((ext_vector_type(4)))  float f32x4;
typedef __attribute__((ext_vector_type(16))) float f32x16;
typedef __attribute__((ext_vector_type(2)))  unsigned uint2v;

// ws layout (bytes):
//   [0, 33554432)            KV fragments: 32 bh x 64 tiles x 8192 B (K|V)
//   [33554432, 67108864)     bf16 partials: 2048 pid x 16384 B (128q x 64d)
//   [67108864, 68157440)     f32 lsums: 2048 pid x 512 B (128 q)
#define WS_KV_BYTES   33554432ull
#define WS_NEED_SPLIT 68157440ull

__device__ __forceinline__ unsigned short f2bf(float f) {
  union { float f; unsigned u; } x; x.f = f;
  unsigned r = x.u + 0x7FFFu + ((x.u >> 16) & 1u);   // RNE
  return (unsigned short)(r >> 16);
}
__device__ __forceinline__ float bf2f(unsigned short u) {
  union { unsigned u; float f; } x; x.u = ((unsigned)u) << 16;
  return x.f;
}
__device__ __forceinline__ unsigned cvtpk_bf16(float lo, float hi) {
  unsigned r;
  asm("v_cvt_pk_bf16_f32 %0, %1, %2" : "=v"(r) : "v"(lo), "v"(hi));
  return r;
}

// ---------------------------------------------------------------------------
// Prepass (verified R5/R6): bf16 K/V in MFMA-fragment order, per 64-key tile
// (16 KB: K 8KB | V 8KB). fattn ds_reads become wave-linear.
// ---------------------------------------------------------------------------
__global__ __launch_bounds__(256)
void prep(const float* __restrict__ Kp, const float* __restrict__ Vp,
          unsigned short* __restrict__ ws) {
  __shared__ unsigned short Kt[128 * DH];
  __shared__ unsigned short Vt[128 * DH];
  const int blk = blockIdx.x;              // bh*32 + t128
  const int bh = blk >> 5, t128 = blk & 31;
  const int b = bh >> 4, h = bh & 15;
  const size_t gbase = (size_t)b * SEQ * DMODEL + (size_t)h * DH +
                       (size_t)t128 * 128 * DMODEL;
  const float* Kb = Kp + gbase;
  const float* Vb = Vp + gbase;
  unsigned short* wt = ws + (size_t)bh * NT64 * 8192 + (size_t)(2 * t128) * 8192;
  const int tid = threadIdx.x;

#pragma unroll
  for (int c = 0; c < 8; ++c) {
    const int idx = c * 256 + tid;
    const int row = idx >> 4, dc = idx & 15;
    f32x4 kf = *(const f32x4*)(Kb + (size_t)row * DMODEL + dc * 4);
    f32x4 vf = *(const f32x4*)(Vb + (size_t)row * DMODEL + dc * 4);
    uint2v ku, vu;
    ku[0] = (unsigned)f2bf(kf[0]) | ((unsigned)f2bf(kf[1]) << 16);
    ku[1] = (unsigned)f2bf(kf[2]) | ((unsigned)f2bf(kf[3]) << 16);
    vu[0] = (unsigned)f2bf(vf[0]) | ((unsigned)f2bf(vf[1]) << 16);
    vu[1] = (unsigned)f2bf(vf[2]) | ((unsigned)f2bf(vf[3]) << 16);
    *(uint2v*)&Kt[row * 64 + dc * 4] = ku;
    *(uint2v*)&Vt[row * 64 + dc * 4] = vu;
  }
  __syncthreads();

#pragma unroll
  for (int c = 0; c < 4; ++c) {            // K fragments
    const int idx = c * 256 + tid;
    const int l31 = idx & 31, hi = (idx >> 5) & 1, d4 = (idx >> 6) & 3, kb = idx >> 8;
    const int tau = kb >> 1, kb2 = kb & 1;
    short8 v = *(const short8*)&Kt[(kb * 32 + l31) * 64 + d4 * 16 + hi * 8];
    *(short8*)&wt[tau * 8192 + (((kb2 * 4 + d4) * 2 + hi) * 32 + l31) * 8] = v;
  }
#pragma unroll
  for (int c = 0; c < 4; ++c) {            // V fragments
    const int idx = c * 256 + tid;
    const int l31 = idx & 31, dt = (idx >> 5) & 1, hi = (idx >> 6) & 1, k16 = idx >> 7;
    const int tau = k16 >> 2, k162 = k16 & 3;
    const int d = dt * 32 + l31, kb0 = k16 * 16 + hi * 8;
    short8 v;
#pragma unroll
    for (int j = 0; j < 8; ++j) v[j] = (short)Vt[(kb0 + j) * 64 + d];
    *(short8*)&wt[tau * 8192 + 4096 + (((k162 * 2 + hi) * 64) + dt * 32 + l31) * 8] = v;
  }
}

// ---- QK^T for one 32-key block: 4 wave-linear ds_read + 4 chained MFMA
// (no setprio: let co-resident waves' exp/VALU issue under our MFMA chain)
__device__ __forceinline__ f32x16 qk_block(const char* Lk, int kbpar, int laneK,
                                           const short8* qb, const f32x16& ZERO) {
  short8 ka0 = *(const short8*)(Lk + kbpar * 4096 + 0 * 1024 + laneK);
  short8 ka1 = *(const short8*)(Lk + kbpar * 4096 + 1 * 1024 + laneK);
  short8 ka2 = *(const short8*)(Lk + kbpar * 4096 + 2 * 1024 + laneK);
  short8 ka3 = *(const short8*)(Lk + kbpar * 4096 + 3 * 1024 + laneK);
  f32x16 z;
  z = __builtin_amdgcn_mfma_f32_32x32x16_bf16(ka0, qb[0], ZERO, 0, 0, 0);
  z = __builtin_amdgcn_mfma_f32_32x32x16_bf16(ka1, qb[1], z, 0, 0, 0);
  z = __builtin_amdgcn_mfma_f32_32x32x16_bf16(ka2, qb[2], z, 0, 0, 0);
  z = __builtin_amdgcn_mfma_f32_32x32x16_bf16(ka3, qb[3], z, 0, 0, 0);
  return z;
}

// ---- shift-free softmax + pack + PV for one 32-key score block
__device__ __forceinline__ void proc_block(f32x16& z, const char* Lv, int k16base,
                                           int laneV, f32x16& accL, f32x16& accH,
                                           float& lsum) {
#pragma unroll
  for (int r = 0; r < 16; ++r) z[r] = __builtin_amdgcn_exp2f(z[r]);
  {
    float s0 = (z[0] + z[1]) + (z[2] + z[3]);
    float s1 = (z[4] + z[5]) + (z[6] + z[7]);
    float s2 = (z[8] + z[9]) + (z[10] + z[11]);
    float s3 = (z[12] + z[13]) + (z[14] + z[15]);
    lsum += (s0 + s1) + (s2 + s3);
  }
#pragma unroll
  for (int s = 0; s < 2; ++s) {
    const int R = 8 * s;
    unsigned a0 = cvtpk_bf16(z[R + 0], z[R + 1]);
    unsigned c0 = cvtpk_bf16(z[R + 4], z[R + 5]);
    unsigned a1 = cvtpk_bf16(z[R + 2], z[R + 3]);
    unsigned c1 = cvtpk_bf16(z[R + 6], z[R + 7]);
    asm("v_permlane32_swap_b32 %0, %1" : "+v"(a0), "+v"(c0));
    asm("v_permlane32_swap_b32 %0, %1" : "+v"(a1), "+v"(c1));
    union { unsigned u[4]; short8 s8; } pw;
    pw.u[0] = a0; pw.u[1] = a1; pw.u[2] = c0; pw.u[3] = c1;
    const int k16 = k16base + s;
    short8 vb0 = *(const short8*)(Lv + k16 * 2048 + laneV);
    short8 vb1 = *(const short8*)(Lv + k16 * 2048 + 512 + laneV);
    accL = __builtin_amdgcn_mfma_f32_32x32x16_bf16(pw.s8, vb0, accL, 0, 0, 0);
    accH = __builtin_amdgcn_mfma_f32_32x32x16_bf16(pw.s8, vb1, accH, 0, 0, 0);
  }
}

// ---------------------------------------------------------------------------
// Flash attention, software-pipelined (depth 1), R6 structure, NO setprio,
// 4 blocks/CU. 4 waves x 32 q = 128 q/block; KT=64 double-buffered (32 KB).
// SPLIT: halves of the KV range -> bf16 partial + f32 lsum (combinable).
// ---------------------------------------------------------------------------
template <bool SPLIT>
__global__ __launch_bounds__(256, 4)
void fattn(const float* __restrict__ Qp,
           const unsigned short* __restrict__ ws,
           float* __restrict__ Op) {
  __shared__ __align__(16) char lds[2][16384];   // [buf][K 8KB | V 8KB]

  const int tid  = threadIdx.x;
  const int lane = tid & 63;
  const int w    = tid >> 6;          // 0..3
  const int hi   = lane >> 5;
  const int l31  = lane & 31;

  int bh, qc, sh, rid;
  if (SPLIT) {                        // 2048 wgs: 256/XCD -> 4 bh per XCD
    const int id = blockIdx.x;
    rid = (id & 7) * 256 + (id >> 3);
    bh = rid >> 6; qc = (rid >> 1) & 31; sh = rid & 1;
  } else {                            // 1024 wgs
    const int id = blockIdx.x;
    rid = (id & 7) * 128 + (id >> 3);
    bh = rid >> 5; qc = rid & 31; sh = 0;
  }
  const int NTloc = SPLIT ? 32 : 64;
  const int t0    = sh * 32;
  const int q0    = qc * 128 + w * 32;

  const int b = bh >> 4, h = bh & 15;
  const float* Qb = Qp + (size_t)b * SEQ * DMODEL + (size_t)h * DH;
  const char* wsb = (const char*)(ws + (size_t)bh * NT64 * 8192);

  // Q B-frag (col=q=l31, k: d = d4*16 + hi*8 + i); folds 1/8 * log2e
  short8 qb[4];
  {
    const float* qr = Qb + (size_t)(q0 + l31) * DMODEL;
    const float sc = 0.125f * LOG2E;
#pragma unroll
    for (int d4 = 0; d4 < 4; ++d4) {
      const float* p = qr + d4 * 16 + hi * 8;
      f32x4 f0 = *(const f32x4*)p;
      f32x4 f1 = *(const f32x4*)(p + 4);
      short8 v;
#pragma unroll
      for (int i = 0; i < 4; ++i) {
        v[i]     = (short)f2bf(f0[i] * sc);
        v[i + 4] = (short)f2bf(f1[i] * sc);
      }
      qb[d4] = v;
    }
  }

  f32x16 ZERO;
#pragma unroll
  for (int r = 0; r < 16; ++r) ZERO[r] = 0.f;
  f32x16 accL = ZERO, accH = ZERO;    // O cols d 0-31 / 32-63
  float lsum = 0.f;

  const int laneK = hi * 512 + l31 * 16;
  const int laneV = hi * 1024 + l31 * 16;

#define STAGE(buf_, tau_)                                                     \
  {                                                                           \
    const char* src_ = wsb + (size_t)(tau_) * 16384;                          \
    char* dst_ = &lds[buf_][0];                                               \
    _Pragma("unroll")                                                         \
    for (int c_ = 0; c_ < 4; ++c_) {                                          \
      __builtin_amdgcn_global_load_lds(                                       \
          (const __attribute__((address_space(1))) void*)(src_ + c_ * 4096 +  \
                                                          tid * 16),          \
          (__attribute__((address_space(3))) void*)(dst_ + c_ * 4096 +        \
                                                    tid * 16),                \
          16, 0, 0);                                                          \
    }                                                                         \
  }

  STAGE(0, t0);
  __syncthreads();

  f32x16 zE, zO;                      // even/odd kb score tiles (pipeline regs)
  for (int t = 0; t < NTloc; ++t) {
    const int cur = t & 1;
    const char* Lk  = &lds[cur][0];
    const char* Lv  = &lds[cur][8192];
    const char* LvO = &lds[cur ^ 1][8192];

    zE = qk_block(Lk, 0, laneK, qb, ZERO);          // kb = 2t
    if (t > 0)
      proc_block(zO, LvO, 2, laneV, accL, accH, lsum);  // kb = 2t-1 (old buf)
    __syncthreads();                                 // all waves done w/ old buf
    if (t + 1 < NTloc) STAGE(cur ^ 1, t0 + t + 1);   // refill old buf
    zO = qk_block(Lk, 1, laneK, qb, ZERO);          // kb = 2t+1
    proc_block(zE, Lv, 0, laneV, accL, accH, lsum); // kb = 2t   (cur buf)
    __syncthreads();                                 // staging landed
  }
  proc_block(zO, &lds[(NTloc - 1) & 1][8192], 2, laneV, accL, accH, lsum);

  if (SPLIT) {
    unsigned short* part =
        (unsigned short*)((char*)const_cast<unsigned short*>(ws) + WS_KV_BYTES) +
        (size_t)rid * 8192;
    float* lout = (float*)((char*)const_cast<unsigned short*>(ws) +
                           2 * WS_KV_BYTES) + (size_t)rid * 128;
    const float lt = lsum + __shfl_xor(lsum, 32, 64);
    if (hi == 0) lout[w * 32 + l31] = lt;
#pragma unroll
    for (int r = 0; r < 16; ++r) {
      const int qrow = (r & 3) + 8 * (r >> 2) + 4 * hi;
      part[(w * 32 + qrow) * 64 + l31]      = f2bf(accL[r]);
      part[(w * 32 + qrow) * 64 + 32 + l31] = f2bf(accH[r]);
    }
  } else {
    const float lt  = lsum + __shfl_xor(lsum, 32, 64);
    const float inv = 1.0f / lt;
#pragma unroll
    for (int r = 0; r < 16; ++r) {
      const int qrow = (r & 3) + 8 * (r >> 2) + 4 * hi;
      const float iv = __shfl(inv, qrow + (lane & 32), 64);
      const size_t row = (size_t)bh * SEQ + q0 + qrow;
      Op[row * DH + l31]      = accL[r] * iv;
      Op[row * DH + 32 + l31] = accH[r] * iv;
    }
  }
#undef STAGE
}

// ---------------------------------------------------------------------------
// Combine: O = (A0 + A1) / (l0 + l1) over the 2 KV shards.
// ---------------------------------------------------------------------------
__global__ __launch_bounds__(256)
void combine(const unsigned short* __restrict__ ws, float* __restrict__ Op) {
  const unsigned short* part = (const unsigned short*)((const char*)ws + WS_KV_BYTES);
  const float* lsum = (const float*)((const char*)ws + 2 * WS_KV_BYTES);
  const int gid = blockIdx.x * 256 + threadIdx.x;   // 1,048,576 threads
  const int bqc = gid >> 10;                        // 0..1023 (bh*32 + qc)
  const int rem = gid & 1023;
  const int q = rem >> 3, dc = rem & 7;
  const int pid0 = bqc * 2, pid1 = pid0 + 1;
  short8 A0 = *(const short8*)&part[(size_t)pid0 * 8192 + q * 64 + dc * 8];
  short8 A1 = *(const short8*)&part[(size_t)pid1 * 8192 + q * 64 + dc * 8];
  const float l = lsum[pid0 * 128 + q] + lsum[pid1 * 128 + q];
  const float inv = 1.0f / l;
  const int bh = bqc >> 5, qc = bqc & 31;
  float* o = Op + ((size_t)bh * SEQ + qc * 128 + q) * DH + dc * 8;
  f32x4 o0, o1;
#pragma unroll
  for (int j = 0; j < 4; ++j) {
    o0[j] = (bf2f((unsigned short)A0[j]) + bf2f((unsigned short)A1[j])) * inv;
    o1[j] = (bf2f((unsigned short)A0[j + 4]) + bf2f((unsigned short)A1[j + 4])) * inv;
  }
  *(f32x4*)o = o0;
  *(f32x4*)(o + 4) = o1;
}

extern "C" void kernel_launch(void* const* d_in, const int* in_sizes, int n_in,
                              void* d_out, int out_size, void* d_ws, size_t ws_size,
                              hipStream_t stream) {
  const float* Q = (const float*)d_in[0];
  const float* K = (const float*)d_in[1];
  const float* V = (const float*)d_in[2];
  float* O = (float*)d_out;
  unsigned short* ws = (unsigned short*)d_ws;

  prep<<<dim3(NBH * 32), dim3(256), 0, stream>>>(K, V, ws);
  if (ws_size >= WS_NEED_SPLIT) {
    fattn<true><<<dim3(2048), dim3(256), 0, stream>>>(Q, ws, O);
    combine<<<dim3(4096), dim3(256), 0, stream>>>(ws, O);
  } else {
    fattn<false><<<dim3(1024), dim3(256), 0, stream>>>(Q, ws, O);
  }
}